// Round 7
// baseline (444.764 us; speedup 1.0000x reference)
//
#include <hip/hip_runtime.h>
#include <hip/hip_bf16.h>
#include <hip/hip_fp16.h>
#include <math.h>

// GuidedUpsampleUnitGF — R7: conv2 VALU-overhead elimination (unrolled taps, linear B layout,
// pointer-bump prefetch); tail: fused guide+stats, head fused into conv3 epilogue (atomics),
// direct border enumeration, padded transpose.

#define P2 65536            // 256*256 pixels
#define PADW 260            // padded image width/height for conv2 (halo 2)

typedef short  frag8  __attribute__((ext_vector_type(8)));   // 8 bf16 (4 VGPRs)
typedef float  f32x4  __attribute__((ext_vector_type(4)));

__device__ __forceinline__ void load16_lds(const void* gsrc, void* lds) {
    __builtin_amdgcn_global_load_lds((const __attribute__((address_space(1))) void*)gsrc,
                                     (__attribute__((address_space(3))) void*)lds, 16, 0, 0);
}

// bilinear 2x upsample coords (half-pixel centers, edge-clamped {0.25,0.75})
struct BilC { int y0, y1, x0, x1; float wy0, wy1, wx0, wx1; };
__device__ __forceinline__ BilC bil_coords(int oy, int ox) {
    BilC c;
    int m = oy >> 1;
    if ((oy & 1) == 0) { c.y0 = (m > 0) ? m - 1 : 0; c.y1 = m; c.wy0 = 0.25f; }
    else               { c.y0 = m; c.y1 = (m < 127) ? m + 1 : 127; c.wy0 = 0.75f; }
    c.wy1 = 1.0f - c.wy0;
    int n = ox >> 1;
    if ((ox & 1) == 0) { c.x0 = (n > 0) ? n - 1 : 0; c.x1 = n; c.wx0 = 0.25f; }
    else               { c.x0 = n; c.x1 = (n < 127) ? n + 1 : 127; c.wx0 = 0.75f; }
    c.wx1 = 1.0f - c.wx0;
    return c;
}
__device__ __forceinline__ float bil_eval(const float* __restrict__ src, const BilC& c) {
    return c.wy0 * (c.wx0 * src[c.y0 * 128 + c.x0] + c.wx1 * src[c.y0 * 128 + c.x1])
         + c.wy1 * (c.wx0 * src[c.y1 * 128 + c.x0] + c.wx1 * src[c.y1 * 128 + c.x1]);
}

// ---------------------------------------------------------------- upsample -> bf16 chunk-planar x
__global__ void upsample_x(const float* __restrict__ mask, const float* __restrict__ fg,
                           const float* __restrict__ bg, const float* __restrict__ feat,
                           __hip_bfloat16* __restrict__ xp) {
    int p = blockIdx.x * 256 + threadIdx.x;
    int chunk = blockIdx.y;
    union { __hip_bfloat16 h[8]; f32x4 v; } u;
    if (chunk >= 33) {
        f32x4 z = {0.f, 0.f, 0.f, 0.f};
        *(f32x4*)&xp[((size_t)chunk * P2 + p) * 8] = z;
        return;
    }
    BilC bc = bil_coords(p >> 8, p & 255);
#pragma unroll
    for (int j = 0; j < 8; j++) {
        int c = chunk * 8 + j;
        float v = 0.f;
        if (c < 263) {
            const float* src = (c == 0) ? mask
                             : (c < 4)  ? fg + (c - 1) * 16384
                             : (c < 7)  ? bg + (c - 4) * 16384
                             :            feat + (c - 7) * 16384;
            v = bil_eval(src, bc);
        }
        u.h[j] = __float2bfloat16(v);
    }
    *(f32x4*)&xp[((size_t)chunk * P2 + p) * 8] = u.v;
}

// ---------------------------------------------------------------- fused guide + stats (LDS tile)
__global__ __launch_bounds__(256) void guide_stats(const float* __restrict__ fg,
                                                   float* __restrict__ guide,
                                                   float* __restrict__ meanI,
                                                   float* __restrict__ varI) {
    __shared__ float G[20 * 21];
    int tid = threadIdx.x;
    int gx0 = blockIdx.x * 16, gy0 = blockIdx.y * 16;
    for (int i = tid; i < 400; i += 256) {
        int r = i / 20, c = i - r * 20;
        int gy = gy0 + r - 2, gx = gx0 + c - 2;
        float v = 0.f;
        if ((unsigned)gy < 256u && (unsigned)gx < 256u) {
            BilC bc = bil_coords(gy, gx);
            v = (bil_eval(fg, bc) + bil_eval(fg + 16384, bc) + bil_eval(fg + 32768, bc))
                * (128.0f / 3.0f);
        }
        G[r * 21 + c] = v;
    }
    __syncthreads();
    int ty = tid >> 4, tx = tid & 15;
    int gy = gy0 + ty, gx = gx0 + tx;
    float s = 0.f, ss = 0.f;
#pragma unroll
    for (int dy = 0; dy < 5; dy++)
#pragma unroll
        for (int dx = 0; dx < 5; dx++) {
            float v = G[(ty + dy) * 21 + tx + dx];
            s += v; ss += v * v;
        }
    int cy = ((gy + 2 < 255) ? gy + 2 : 255) - ((gy - 2 > 0) ? gy - 2 : 0) + 1;
    int cx = ((gx + 2 < 255) ? gx + 2 : 255) - ((gx - 2 > 0) ? gx - 2 : 0) + 1;
    float inv = 1.0f / (float)(cy * cx);
    float m = s * inv;
    guide[gy * 256 + gx] = G[(ty + 2) * 21 + tx + 2];
    meanI[gy * 256 + gx] = m;
    varI[gy * 256 + gx]  = ss * inv - m * m;
}

// ---------------------------------------------------------------- merged prep
// blocks: [0,129) border zero (direct enum) | [129,193) haccum zero | [193,993) w2 repack
//         [993,1029) w1 repack | [1029,1061) w3 repack
__global__ void prep_all(const float* __restrict__ w2, const float* __restrict__ w1,
                         const float* __restrict__ w3,
                         __hip_bfloat16* __restrict__ wpk2, __hip_bfloat16* __restrict__ wpk1,
                         __hip_bfloat16* __restrict__ wpk3, __hip_bfloat16* __restrict__ y1p,
                         float* __restrict__ haccum) {
    int b = blockIdx.x;
    int tid = threadIdx.x;
    if (b < 129) {                                     // 2064 border px * 16 chunks = 33024
        int idx = b * 256 + tid;
        if (idx >= 33024) return;
        int pid = idx >> 4, chunk = idx & 15;
        int py, px;
        if (pid < 520)       { py = pid / 260;               px = pid - (py) * 260; }
        else if (pid < 1040) { int t = pid - 520; int r = t / 260; py = 258 + r; px = t - r * 260; }
        else                 { int t = pid - 1040; int r = t >> 2; int c = t & 3;
                               py = 2 + r; px = (c < 2) ? c : 256 + c; }
        f32x4 z = {0.f, 0.f, 0.f, 0.f};
        f32x4* dst = (f32x4*)&y1p[((size_t)py * PADW + px) * 256 + chunk * 16];
        dst[0] = z; dst[1] = z;
    } else if (b < 193) {                              // haccum zero: 64 blocks * 256 * 4 = 65536
        int idx = (b - 193 + 64) * 256 + tid - 64 * 256;   // = (b-129)*256+tid
        idx = (b - 129) * 256 + tid;
        f32x4 z = {0.f, 0.f, 0.f, 0.f};
        *(f32x4*)&haccum[idx * 4] = z;
    } else if (b < 993) {                              // w2 -> [ict][tap][nb][lane][8]
        int idx = (b - 193) * 256 + tid;               // 204800
        int lane = idx & 63;
        int nb = (idx >> 6) & 15;
        int t2 = idx >> 10;                            // 0..199
        int tap = t2 % 25, ict = t2 / 25;
        int oc = nb * 16 + (lane & 15);
        int ic0 = ict * 32 + (lane >> 4) * 8;
        union { __hip_bfloat16 h[8]; f32x4 v; } u;
#pragma unroll
        for (int j = 0; j < 8; j++)
            u.h[j] = __float2bfloat16(w2[(oc * 256 + ic0 + j) * 25 + tap]);
        *(f32x4*)&wpk2[(size_t)idx * 8] = u.v;
    } else {
        const float* W; __hip_bfloat16* dst; int K, KT, idx;
        if (b < 1029) { W = w1; dst = wpk1; K = 263; KT = 9; idx = (b - 993) * 256 + tid; }
        else          { W = w3; dst = wpk3; K = 256; KT = 8; idx = (b - 1029) * 256 + tid; }
        if (idx >= KT * 16 * 64) return;
        int lane = idx & 63;
        int nbg = (idx >> 6) & 15;
        int kt = idx >> 10;
        int oc = nbg * 16 + (lane & 15);
        int ic0 = kt * 32 + (lane >> 4) * 8;
        union { __hip_bfloat16 h[8]; f32x4 v; } u;
#pragma unroll
        for (int j = 0; j < 8; j++) {
            int ic = ic0 + j;
            u.h[j] = (ic < K) ? __float2bfloat16(W[(size_t)oc * K + ic]) : __float2bfloat16(0.f);
        }
        *(f32x4*)&dst[(size_t)idx * 8] = u.v;
    }
}

// ---------------------------------------------------------------- generic 1x1 MFMA GEMM
// MODE 0: bf16 padded NHWC (+relu) -> y1p via LDS restage. MODE 1: fp32 planar (+relu) -> out,
// plus fused mask-head partials (wm-weighted oc-reduction -> atomicAdd haccum).
template<int MODE>
__global__ __launch_bounds__(256) void mfma_1x1(const __hip_bfloat16* __restrict__ xch,
                                                const __hip_bfloat16* __restrict__ wpk,
                                                const float* __restrict__ bias,
                                                void* __restrict__ outp, int KT,
                                                const float* __restrict__ wmv,
                                                float* __restrict__ haccum) {
    __shared__ __align__(16) char smem[MODE == 0 ? 34816 : 32768];
    __hip_bfloat16* Asm0 = (__hip_bfloat16*)smem;                 // [2][128*32]
    __hip_bfloat16* Bsm0 = (__hip_bfloat16*)(smem + 16384);       // [2][8*64*8]
    const int tid = threadIdx.x;
    const int wave = tid >> 6, lane = tid & 63;
    const int q = lane >> 4, m16 = lane & 15;
    const int wm = wave & 1, wn = wave >> 1;
    const int pb = blockIdx.x * 128, oh = blockIdx.y;

    f32x4 acc[4][4] = {};

    auto stA = [&](int kt, int buf) {
#pragma unroll
        for (int it = 0; it < 2; it++) {
            int chb = it * 256 + wave * 64;
            int ch = chb + lane;
            int px = ch >> 2, oct = ch & 3;
            const __hip_bfloat16* src = xch + ((size_t)(kt * 4 + oct) * P2 + pb + px) * 8;
            load16_lds(src, &Asm0[(size_t)buf * 4096 + chb * 8]);
        }
    };
    auto stB = [&](int kt, int buf) {
#pragma unroll
        for (int it = 0; it < 2; it++) {
            int chb = it * 256 + wave * 64;
            int ch = chb + lane;
            int nb = ch >> 6, l = ch & 63;
            const __hip_bfloat16* src = wpk + (((size_t)kt * 16 + oh * 8 + nb) * 64 + l) * 8;
            load16_lds(src, &Bsm0[(size_t)buf * 4096 + chb * 8]);
        }
    };
    stA(0, 0); stB(0, 0);
    int buf = 0;
    for (int kt = 0; kt < KT; kt++) {
        __syncthreads();
        if (kt + 1 < KT) { stA(kt + 1, buf ^ 1); stB(kt + 1, buf ^ 1); }
        frag8 a[4], b[4];
#pragma unroll
        for (int i = 0; i < 4; i++)
            a[i] = *(const frag8*)&Asm0[(size_t)buf * 4096 + ((wm * 4 + i) * 16 + m16) * 32 + q * 8];
#pragma unroll
        for (int j = 0; j < 4; j++)
            b[j] = *(const frag8*)&Bsm0[(size_t)buf * 4096 + ((wn * 4 + j) * 64 + lane) * 8];
#pragma unroll
        for (int i = 0; i < 4; i++)
#pragma unroll
            for (int j = 0; j < 4; j++)
                acc[i][j] = __builtin_amdgcn_mfma_f32_16x16x32_bf16(a[i], b[j], acc[i][j], 0, 0, 0);
        buf ^= 1;
    }
    if (MODE == 0) {
        __syncthreads();
        __hip_bfloat16* Ct = (__hip_bfloat16*)smem;
#pragma unroll
        for (int j = 0; j < 4; j++) {
            int ocr = (wn * 4 + j) * 16 + m16;
            float bj = bias[oh * 128 + ocr];
#pragma unroll
            for (int i = 0; i < 4; i++) {
                f32x4 v = acc[i][j];
#pragma unroll
                for (int e = 0; e < 4; e++) {
                    int pxr = (wm * 4 + i) * 16 + q * 4 + e;
                    float tv = v[e] + bj;
                    Ct[pxr * 136 + ocr] = __float2bfloat16(tv > 0.f ? tv : 0.f);
                }
            }
        }
        __syncthreads();
        __hip_bfloat16* y1p = (__hip_bfloat16*)outp;
        int colr = (tid & 15) * 8;
#pragma unroll
        for (int it = 0; it < 8; it++) {
            int pxr = it * 16 + (tid >> 4);
            int pix = pb + pxr;
            int py = pix >> 8, px = pix & 255;
            f32x4 val = *(f32x4*)&Ct[pxr * 136 + colr];
            *(f32x4*)&y1p[((size_t)(py + 2) * PADW + px + 2) * 256 + oh * 128 + colr] = val;
        }
    } else {
        float* outf = (float*)outp;
        float hpart[4][4] = {};
#pragma unroll
        for (int j = 0; j < 4; j++) {
            int oc = oh * 128 + (wn * 4 + j) * 16 + m16;
            float bj = bias[oc];
            float wj = wmv[oc];
#pragma unroll
            for (int i = 0; i < 4; i++) {
                f32x4 v = acc[i][j];
#pragma unroll
                for (int e = 0; e < 4; e++) {
                    float tv = v[e] + bj;
                    tv = tv > 0.f ? tv : 0.f;
                    v[e] = tv;
                    hpart[i][e] += wj * tv;
                }
                *(f32x4*)&outf[(size_t)oc * P2 + pb + (wm * 4 + i) * 16 + q * 4] = v;
            }
        }
        // reduce hpart over the 16 m16-lanes (same pixel set), then one atomic per pixel
#pragma unroll
        for (int i = 0; i < 4; i++)
#pragma unroll
            for (int e = 0; e < 4; e++) {
                float s = hpart[i][e];
                s += __shfl_xor(s, 1);
                s += __shfl_xor(s, 2);
                s += __shfl_xor(s, 4);
                s += __shfl_xor(s, 8);
                if (m16 == 0)
                    atomicAdd(&haccum[pb + (wm * 4 + i) * 16 + q * 4 + e], s);
            }
    }
}

// ---------------------------------------------------------------- conv2: 5x5 MFMA, R7 core
// Fully unrolled 25-tap inner loop; B linear layout [ict][tap][nb][lane][8], pointer-bump
// register prefetch; A LDS double-buffer, 1 barrier per ict.
__global__ __launch_bounds__(128, 2) void conv5x5_mfma(const __hip_bfloat16* __restrict__ y1p,
                                                       const __hip_bfloat16* __restrict__ wpk,
                                                       const float* __restrict__ bias,
                                                       __half* __restrict__ pf) {
    __shared__ __align__(16) __hip_bfloat16 Asm[2][12 * 20 * 32];  // 2 x 15360 B
    const int tid = threadIdx.x;
    const int wave = tid >> 6;
    const int lane = tid & 63;
    const int q = lane >> 4;
    const int m16 = lane & 15;
    const int bx = blockIdx.x, by = blockIdx.y, oh = blockIdx.z;

    f32x4 acc[4][8] = {};

    auto stageA = [&](int ict, int buf) {
#pragma unroll
        for (int g = 0; g < 8; g++) {
            int grp = g * 2 + wave;
            if (grp >= 15) break;
            int chb = grp * 64;
            int ch = chb + lane;
            int oct = ch & 3, pl = ch >> 2;
            int pc = pl % 20, pr = pl / 20;
            const __hip_bfloat16* src =
                y1p + (size_t)((by * 8 + pr) * PADW + bx * 16 + pc) * 256 + ict * 32 + oct * 8;
            load16_lds(src, &Asm[buf][chb * 8]);
        }
    };

    const __hip_bfloat16* bptr = wpk + ((size_t)(oh * 8) * 64 + lane) * 8;
    frag8 b[2][8];
    auto loadB = [&](frag8* dst) {
#pragma unroll
        for (int j = 0; j < 8; j++)
            dst[j] = *(const frag8*)(bptr + j * 512);
        bptr += 8192;                                 // one tap step (16 nb * 64 lanes * 8)
    };

    stageA(0, 0);
    loadB(b[0]);
    int abuf = 0;

    for (int ict = 0; ict < 8; ict++) {
        __syncthreads();                              // A[abuf] staged (drains vmcnt)
        const __hip_bfloat16* aptr = &Asm[abuf][(wave * 80 + m16) * 32 + q * 8];
#pragma unroll
        for (int tap = 0; tap < 25; tap++) {
            const int dy = tap / 5, dx = tap % 5;     // compile-time after unroll
            if (tap < 24) loadB(b[(tap + 1) & 1]);    // register prefetch (distinct parity)
            else if (ict < 7) stageA(ict + 1, abuf ^ 1);
            frag8 a[4];
#pragma unroll
            for (int i = 0; i < 4; i++)
                a[i] = *(const frag8*)(aptr + ((i + dy) * 20 + dx) * 32);
            frag8* bc = b[tap & 1];
#pragma unroll
            for (int i = 0; i < 4; i++)
#pragma unroll
                for (int j = 0; j < 8; j++)
                    acc[i][j] = __builtin_amdgcn_mfma_f32_16x16x32_bf16(a[i], bc[j], acc[i][j], 0, 0, 0);
            if (tap == 24 && ict < 7) loadB(b[0]);    // next ict's tap0 (after consuming b[0])
        }
        abuf ^= 1;
    }

    // epilogue: fp16 out, 8B stores
#pragma unroll
    for (int j = 0; j < 8; j++) {
        int oc = oh * 128 + j * 16 + m16;
        float bj = bias[oc];
#pragma unroll
        for (int i = 0; i < 4; i++) {
            int r = wave * 4 + i;
            f32x4 v = acc[i][j];
            union { __half h[4]; double d; } u;
#pragma unroll
            for (int e = 0; e < 4; e++) {
                float t = v[e] + bj;
                u.h[e] = __float2half(t > 0.f ? t : 0.f);
            }
            *(double*)&pf[(size_t)oc * P2 + (by * 8 + r) * 256 + bx * 16 + q * 4] = u.d;
        }
    }
}

// ---------------------------------------------------------------- guided filter: streaming separable
__global__ __launch_bounds__(256) void gf_stream(const __half* __restrict__ p,
                                                 const float* __restrict__ guide,
                                                 const float* __restrict__ meanI,
                                                 const float* __restrict__ varI,
                                                 __hip_bfloat16* __restrict__ filt) {
    __shared__ float Prow[260], IProw[260], Arow[260], Brow[260];
    const int t = threadIdx.x;
    const int c = blockIdx.y;
    const int Y0 = blockIdx.x * 64;
    const __half* pc = p + (size_t)c * P2;
    if (t < 4) {
        int e = (t < 2) ? t : 256 + t;
        Prow[e] = 0.f; IProw[e] = 0.f; Arow[e] = 0.f; Brow[e] = 0.f;
    }
    int xlo = (t - 2 > 0) ? t - 2 : 0, xhi = (t + 2 < 255) ? t + 2 : 255;
    const float cxr = 1.0f / (float)(xhi - xlo + 1);
    float hp[5] = {0, 0, 0, 0, 0}, hip[5] = {0, 0, 0, 0, 0};
    float ha[5] = {0, 0, 0, 0, 0}, hb[5] = {0, 0, 0, 0, 0};
    float vp = 0.f, vip = 0.f, va = 0.f, vb = 0.f;
    __syncthreads();
    for (int s = 0; s < 72; s++) {
        int yL = Y0 - 4 + s;
        bool okL = ((unsigned)yL < 256u);
        if (okL) {
            float pv = __half2float(pc[yL * 256 + t]);
            Prow[t + 2] = pv;
            IProw[t + 2] = guide[yL * 256 + t] * pv;
        }
        __syncthreads();
        float hpn = 0.f, hipn = 0.f;
        if (okL) {
            hpn  = Prow[t] + Prow[t + 1] + Prow[t + 2] + Prow[t + 3] + Prow[t + 4];
            hipn = IProw[t] + IProw[t + 1] + IProw[t + 2] + IProw[t + 3] + IProw[t + 4];
        }
        vp += hpn - hp[0];  vip += hipn - hip[0];
        hp[0] = hp[1]; hp[1] = hp[2]; hp[2] = hp[3]; hp[3] = hp[4]; hp[4] = hpn;
        hip[0] = hip[1]; hip[1] = hip[2]; hip[2] = hip[3]; hip[3] = hip[4]; hip[4] = hipn;
        int yA = yL - 2;
        float aV = 0.f, bV = 0.f;
        if ((unsigned)yA < 256u && yA >= Y0 - 2) {
            int ylo = (yA - 2 > 0) ? yA - 2 : 0, yhi = (yA + 2 < 255) ? yA + 2 : 255;
            float inv1 = cxr / (float)(yhi - ylo + 1);
            float mI = meanI[yA * 256 + t], vI = varI[yA * 256 + t];
            float mp = vp * inv1, mip = vip * inv1;
            float cov = mip - mI * mp;
            aV = cov / (vI + 0.01f);
            bV = mp - aV * mI;
        }
        Arow[t + 2] = aV;
        Brow[t + 2] = bV;
        __syncthreads();
        float han = Arow[t] + Arow[t + 1] + Arow[t + 2] + Arow[t + 3] + Arow[t + 4];
        float hbn = Brow[t] + Brow[t + 1] + Brow[t + 2] + Brow[t + 3] + Brow[t + 4];
        va += han - ha[0];  vb += hbn - hb[0];
        ha[0] = ha[1]; ha[1] = ha[2]; ha[2] = ha[3]; ha[3] = ha[4]; ha[4] = han;
        hb[0] = hb[1]; hb[1] = hb[2]; hb[2] = hb[3]; hb[3] = hb[4]; hb[4] = hbn;
        int yo = yL - 4;
        if (yo >= Y0 && yo < Y0 + 64 && (unsigned)yo < 256u) {
            int ylo = (yo - 2 > 0) ? yo - 2 : 0, yhi = (yo + 2 < 255) ? yo + 2 : 255;
            float inv2 = cxr / (float)(yhi - ylo + 1);
            float I = guide[yo * 256 + t];
            filt[(size_t)c * P2 + yo * 256 + t] = __float2bfloat16((va * I + vb) * inv2);
        }
    }
}

// ---------------------------------------------------------------- transpose bf16 [c][p] -> chunk-planar
__global__ void transpose_cp(const __hip_bfloat16* __restrict__ filt,
                             __hip_bfloat16* __restrict__ filtp) {
    __shared__ __hip_bfloat16 T[8][1032];           // pad 1024->1032 breaks 8-way read conflicts
    int tid = threadIdx.x;
    int p0 = blockIdx.x * 1024;
    int cg = blockIdx.y;
    for (int i = tid; i < 4096; i += 256) {          // 4B (2px) loads
        int r = i >> 9, pl2 = (i & 511) * 2;
        unsigned v = *(const unsigned*)&filt[(size_t)(cg * 8 + r) * P2 + p0 + pl2];
        *(unsigned*)&T[r][pl2] = v;
    }
    __syncthreads();
    for (int pl = tid; pl < 1024; pl += 256) {
        union { __hip_bfloat16 h[8]; f32x4 v; } u;
#pragma unroll
        for (int j = 0; j < 8; j++) u.h[j] = T[j][pl];
        *(f32x4*)&filtp[((size_t)cg * P2 + p0 + pl) * 8] = u.v;
    }
}

// ---------------------------------------------------------------- sigmoid head finalize
__global__ void sigmoid_head(const float* __restrict__ haccum, const float* __restrict__ bm,
                             float* __restrict__ out) {
    int p = blockIdx.x * 256 + threadIdx.x;
    out[p] = 1.0f / (1.0f + expf(-(haccum[p] + bm[0])));
}

// ---------------------------------------------------------------- launch
extern "C" void kernel_launch(void* const* d_in, const int* in_sizes, int n_in,
                              void* d_out, int out_size, void* d_ws, size_t ws_size,
                              hipStream_t stream) {
    const float* fg   = (const float*)d_in[0];
    const float* bg   = (const float*)d_in[1];
    const float* mask = (const float*)d_in[2];
    const float* feat = (const float*)d_in[3];
    const float* w1   = (const float*)d_in[4];
    const float* b1   = (const float*)d_in[5];
    const float* w2   = (const float*)d_in[6];
    const float* b2   = (const float*)d_in[7];
    const float* w3   = (const float*)d_in[8];
    const float* b3   = (const float*)d_in[9];
    const float* wm   = (const float*)d_in[10];
    const float* bm   = (const float*)d_in[11];
    float* out = (float*)d_out;
    char* w8 = (char*)d_ws;

    __half* pbuf          = (__half*)w8;                         // 33,554,432 B
    __hip_bfloat16* filtp = (__hip_bfloat16*)(w8 + 33554432);    // 33,554,432 B
    __hip_bfloat16* xp    = (__hip_bfloat16*)(w8 + 67108864);    // 37,748,736 B
    __hip_bfloat16* filt  = (__hip_bfloat16*)(w8 + 67108864);    // alias xp
    __hip_bfloat16* y1p   = (__hip_bfloat16*)(w8 + 104857600);   // 34,611,200 B
    __hip_bfloat16* wpk2  = (__hip_bfloat16*)(w8 + 139468800);   // 3,276,800 B
    __hip_bfloat16* wpk1  = (__hip_bfloat16*)(w8 + 142745600);   // 147,456 B
    __hip_bfloat16* wpk3  = (__hip_bfloat16*)(w8 + 142893056);   // 131,072 B
    float* guide  = (float*)(w8 + 143024128);
    float* meanI  = guide + P2;
    float* varI   = meanI + P2;
    float* haccum = varI + P2;

    // 1. upsample + concat -> xp
    upsample_x<<<dim3(256, 36), 256, 0, stream>>>(mask, fg, bg, feat, xp);
    // 2. fused guide + stats
    guide_stats<<<dim3(16, 16), 256, 0, stream>>>(fg, guide, meanI, varI);
    // 3. merged prep (border zero + haccum zero + 3 repacks)
    prep_all<<<1061, 256, 0, stream>>>(w2, w1, w3, wpk2, wpk1, wpk3, y1p, haccum);
    // 4. conv1 (1x1 MFMA) -> y1p
    mfma_1x1<0><<<dim3(512, 2), 256, 0, stream>>>(xp, wpk1, b1, y1p, 9, nullptr, nullptr);
    // 5. conv2 (5x5 MFMA) -> pbuf (fp16 [c][p])
    conv5x5_mfma<<<dim3(16, 32, 2), 128, 0, stream>>>(y1p, wpk2, b2, pbuf);
    // 6. guided filter -> filt (bf16 [c][p])
    gf_stream<<<dim3(4, 256), 256, 0, stream>>>(pbuf, guide, meanI, varI, filt);
    // 7. transpose -> filtp
    transpose_cp<<<dim3(64, 32), 256, 0, stream>>>(filt, filtp);
    // 8. conv3 (1x1 MFMA, fused head partials) -> out+P2 & haccum
    mfma_1x1<1><<<dim3(512, 2), 256, 0, stream>>>(filtp, wpk3, b3, out + P2, 8, wm, haccum);
    // 9. sigmoid head -> out[0..P2)
    sigmoid_head<<<256, 256, 0, stream>>>(haccum, bm, out);
}

// Round 8
// 434.207 us; speedup vs baseline: 1.0243x; 1.0243x over previous
//
#include <hip/hip_runtime.h>
#include <hip/hip_bf16.h>
#include <hip/hip_fp16.h>
#include <math.h>

// GuidedUpsampleUnitGF — R8: conv2 reverted to R6 core (R7 unroll spilled: WRITE_SIZE 33->61MB).
// 1x1 convs merged over oh: 128px x 256oc per block (half the blocks, half the A traffic).

#define P2 65536            // 256*256 pixels
#define PADW 260            // padded image width/height for conv2 (halo 2)

typedef short  frag8  __attribute__((ext_vector_type(8)));   // 8 bf16 (4 VGPRs)
typedef float  f32x4  __attribute__((ext_vector_type(4)));

__device__ __forceinline__ void load16_lds(const void* gsrc, void* lds) {
    __builtin_amdgcn_global_load_lds((const __attribute__((address_space(1))) void*)gsrc,
                                     (__attribute__((address_space(3))) void*)lds, 16, 0, 0);
}

// bilinear 2x upsample coords (half-pixel centers, edge-clamped {0.25,0.75})
struct BilC { int y0, y1, x0, x1; float wy0, wy1, wx0, wx1; };
__device__ __forceinline__ BilC bil_coords(int oy, int ox) {
    BilC c;
    int m = oy >> 1;
    if ((oy & 1) == 0) { c.y0 = (m > 0) ? m - 1 : 0; c.y1 = m; c.wy0 = 0.25f; }
    else               { c.y0 = m; c.y1 = (m < 127) ? m + 1 : 127; c.wy0 = 0.75f; }
    c.wy1 = 1.0f - c.wy0;
    int n = ox >> 1;
    if ((ox & 1) == 0) { c.x0 = (n > 0) ? n - 1 : 0; c.x1 = n; c.wx0 = 0.25f; }
    else               { c.x0 = n; c.x1 = (n < 127) ? n + 1 : 127; c.wx0 = 0.75f; }
    c.wx1 = 1.0f - c.wx0;
    return c;
}
__device__ __forceinline__ float bil_eval(const float* __restrict__ src, const BilC& c) {
    return c.wy0 * (c.wx0 * src[c.y0 * 128 + c.x0] + c.wx1 * src[c.y0 * 128 + c.x1])
         + c.wy1 * (c.wx0 * src[c.y1 * 128 + c.x0] + c.wx1 * src[c.y1 * 128 + c.x1]);
}

// ---------------------------------------------------------------- upsample -> bf16 chunk-planar x
__global__ void upsample_x(const float* __restrict__ mask, const float* __restrict__ fg,
                           const float* __restrict__ bg, const float* __restrict__ feat,
                           __hip_bfloat16* __restrict__ xp) {
    int p = blockIdx.x * 256 + threadIdx.x;
    int chunk = blockIdx.y;
    union { __hip_bfloat16 h[8]; f32x4 v; } u;
    if (chunk >= 33) {
        f32x4 z = {0.f, 0.f, 0.f, 0.f};
        *(f32x4*)&xp[((size_t)chunk * P2 + p) * 8] = z;
        return;
    }
    BilC bc = bil_coords(p >> 8, p & 255);
#pragma unroll
    for (int j = 0; j < 8; j++) {
        int c = chunk * 8 + j;
        float v = 0.f;
        if (c < 263) {
            const float* src = (c == 0) ? mask
                             : (c < 4)  ? fg + (c - 1) * 16384
                             : (c < 7)  ? bg + (c - 4) * 16384
                             :            feat + (c - 7) * 16384;
            v = bil_eval(src, bc);
        }
        u.h[j] = __float2bfloat16(v);
    }
    *(f32x4*)&xp[((size_t)chunk * P2 + p) * 8] = u.v;
}

// ---------------------------------------------------------------- fused guide + stats (LDS tile)
__global__ __launch_bounds__(256) void guide_stats(const float* __restrict__ fg,
                                                   float* __restrict__ guide,
                                                   float* __restrict__ meanI,
                                                   float* __restrict__ varI) {
    __shared__ float G[20 * 21];
    int tid = threadIdx.x;
    int gx0 = blockIdx.x * 16, gy0 = blockIdx.y * 16;
    for (int i = tid; i < 400; i += 256) {
        int r = i / 20, c = i - r * 20;
        int gy = gy0 + r - 2, gx = gx0 + c - 2;
        float v = 0.f;
        if ((unsigned)gy < 256u && (unsigned)gx < 256u) {
            BilC bc = bil_coords(gy, gx);
            v = (bil_eval(fg, bc) + bil_eval(fg + 16384, bc) + bil_eval(fg + 32768, bc))
                * (128.0f / 3.0f);
        }
        G[r * 21 + c] = v;
    }
    __syncthreads();
    int ty = tid >> 4, tx = tid & 15;
    int gy = gy0 + ty, gx = gx0 + tx;
    float s = 0.f, ss = 0.f;
#pragma unroll
    for (int dy = 0; dy < 5; dy++)
#pragma unroll
        for (int dx = 0; dx < 5; dx++) {
            float v = G[(ty + dy) * 21 + tx + dx];
            s += v; ss += v * v;
        }
    int cy = ((gy + 2 < 255) ? gy + 2 : 255) - ((gy - 2 > 0) ? gy - 2 : 0) + 1;
    int cx = ((gx + 2 < 255) ? gx + 2 : 255) - ((gx - 2 > 0) ? gx - 2 : 0) + 1;
    float inv = 1.0f / (float)(cy * cx);
    float m = s * inv;
    guide[gy * 256 + gx] = G[(ty + 2) * 21 + tx + 2];
    meanI[gy * 256 + gx] = m;
    varI[gy * 256 + gx]  = ss * inv - m * m;
}

// ---------------------------------------------------------------- merged prep
// blocks: [0,129) border zero | [129,193) haccum zero | [193,993) w2 repack (R6 layout)
//         [993,1029) w1 repack | [1029,1061) w3 repack
__global__ void prep_all(const float* __restrict__ w2, const float* __restrict__ w1,
                         const float* __restrict__ w3,
                         __hip_bfloat16* __restrict__ wpk2, __hip_bfloat16* __restrict__ wpk1,
                         __hip_bfloat16* __restrict__ wpk3, __hip_bfloat16* __restrict__ y1p,
                         float* __restrict__ haccum) {
    int b = blockIdx.x;
    int tid = threadIdx.x;
    if (b < 129) {                                     // 2064 border px * 16 chunks = 33024
        int idx = b * 256 + tid;
        if (idx >= 33024) return;
        int pid = idx >> 4, chunk = idx & 15;
        int py, px;
        if (pid < 520)       { py = pid / 260;               px = pid - (py) * 260; }
        else if (pid < 1040) { int t = pid - 520; int r = t / 260; py = 258 + r; px = t - r * 260; }
        else                 { int t = pid - 1040; int r = t >> 2; int c = t & 3;
                               py = 2 + r; px = (c < 2) ? c : 256 + c; }
        f32x4 z = {0.f, 0.f, 0.f, 0.f};
        f32x4* dst = (f32x4*)&y1p[((size_t)py * PADW + px) * 256 + chunk * 16];
        dst[0] = z; dst[1] = z;
    } else if (b < 193) {                              // haccum zero: 64 blocks * 1024 floats
        int idx = (b - 129) * 256 + tid;
        f32x4 z = {0.f, 0.f, 0.f, 0.f};
        *(f32x4*)&haccum[idx * 4] = z;
    } else if (b < 993) {                              // w2 -> [tap][ict][nb][lane][8]  (R6 layout)
        int idx = (b - 193) * 256 + tid;               // 204800
        int lane = idx & 63;
        int nb = (idx >> 6) & 15;
        int kt = (idx >> 10) & 7;
        int t  = idx >> 13;
        int oc = nb * 16 + (lane & 15);
        int ic0 = kt * 32 + (lane >> 4) * 8;
        union { __hip_bfloat16 h[8]; f32x4 v; } u;
#pragma unroll
        for (int j = 0; j < 8; j++)
            u.h[j] = __float2bfloat16(w2[(oc * 256 + ic0 + j) * 25 + t]);
        *(f32x4*)&wpk2[(size_t)idx * 8] = u.v;
    } else {
        const float* W; __hip_bfloat16* dst; int K, KT, idx;
        if (b < 1029) { W = w1; dst = wpk1; K = 263; KT = 9; idx = (b - 993) * 256 + tid; }
        else          { W = w3; dst = wpk3; K = 256; KT = 8; idx = (b - 1029) * 256 + tid; }
        if (idx >= KT * 16 * 64) return;
        int lane = idx & 63;
        int nbg = (idx >> 6) & 15;
        int kt = idx >> 10;
        int oc = nbg * 16 + (lane & 15);
        int ic0 = kt * 32 + (lane >> 4) * 8;
        union { __hip_bfloat16 h[8]; f32x4 v; } u;
#pragma unroll
        for (int j = 0; j < 8; j++) {
            int ic = ic0 + j;
            u.h[j] = (ic < K) ? __float2bfloat16(W[(size_t)oc * K + ic]) : __float2bfloat16(0.f);
        }
        *(f32x4*)&dst[(size_t)idx * 8] = u.v;
    }
}

// ---------------------------------------------------------------- 1x1 MFMA GEMM, merged oh
// block: 128 px x 256 oc; 4 waves, each 8M x 4N. grid (512).
// MODE 0: bf16 padded NHWC (+relu) -> y1p via LDS restage. MODE 1: fp32 planar (+relu) -> out
// plus fused mask-head partials (wm-weighted oc-reduction -> atomicAdd haccum).
template<int MODE>
__global__ __launch_bounds__(256) void mfma_1x1(const __hip_bfloat16* __restrict__ xch,
                                                const __hip_bfloat16* __restrict__ wpk,
                                                const float* __restrict__ bias,
                                                void* __restrict__ outp, int KT,
                                                const float* __restrict__ wmv,
                                                float* __restrict__ haccum) {
    __shared__ __align__(16) char smem[MODE == 0 ? 67584 : 49152];
    __hip_bfloat16* Asm0 = (__hip_bfloat16*)smem;                 // [2][128*32]   16 KB
    __hip_bfloat16* Bsm0 = (__hip_bfloat16*)(smem + 16384);       // [2][16*64*8]  32 KB
    const int tid = threadIdx.x;
    const int wave = tid >> 6, lane = tid & 63;
    const int q = lane >> 4, m16 = lane & 15;
    const int wn = wave;                              // N quarter (64 oc)
    const int pb = blockIdx.x * 128;

    f32x4 acc[8][4] = {};

    auto stA = [&](int kt, int buf) {
#pragma unroll
        for (int it = 0; it < 2; it++) {
            int chb = it * 256 + wave * 64;
            int ch = chb + lane;
            int px = ch >> 2, oct = ch & 3;
            const __hip_bfloat16* src = xch + ((size_t)(kt * 4 + oct) * P2 + pb + px) * 8;
            load16_lds(src, &Asm0[(size_t)buf * 4096 + chb * 8]);
        }
    };
    auto stB = [&](int kt, int buf) {
#pragma unroll
        for (int it = 0; it < 4; it++) {
            int chb = it * 256 + wave * 64;
            int ch = chb + lane;
            int nb = ch >> 6, l = ch & 63;
            const __hip_bfloat16* src = wpk + (((size_t)kt * 16 + nb) * 64 + l) * 8;
            load16_lds(src, &Bsm0[(size_t)buf * 8192 + chb * 8]);
        }
    };
    stA(0, 0); stB(0, 0);
    int buf = 0;
    for (int kt = 0; kt < KT; kt++) {
        __syncthreads();
        if (kt + 1 < KT) { stA(kt + 1, buf ^ 1); stB(kt + 1, buf ^ 1); }
        frag8 a[8], b[4];
#pragma unroll
        for (int i = 0; i < 8; i++)
            a[i] = *(const frag8*)&Asm0[(size_t)buf * 4096 + (i * 16 + m16) * 32 + q * 8];
#pragma unroll
        for (int j = 0; j < 4; j++)
            b[j] = *(const frag8*)&Bsm0[(size_t)buf * 8192 + ((wn * 4 + j) * 64 + lane) * 8];
#pragma unroll
        for (int i = 0; i < 8; i++)
#pragma unroll
            for (int j = 0; j < 4; j++)
                acc[i][j] = __builtin_amdgcn_mfma_f32_16x16x32_bf16(a[i], b[j], acc[i][j], 0, 0, 0);
        buf ^= 1;
    }
    if (MODE == 0) {
        // restage through LDS: Ct[128 px][264 oc-stride], then coalesced 16B global stores
        __syncthreads();
        __hip_bfloat16* Ct = (__hip_bfloat16*)smem;
#pragma unroll
        for (int j = 0; j < 4; j++) {
            int ocr = (wn * 4 + j) * 16 + m16;
            float bj = bias[ocr];
#pragma unroll
            for (int i = 0; i < 8; i++) {
                f32x4 v = acc[i][j];
#pragma unroll
                for (int e = 0; e < 4; e++) {
                    int pxr = i * 16 + q * 4 + e;
                    float tv = v[e] + bj;
                    Ct[pxr * 264 + ocr] = __float2bfloat16(tv > 0.f ? tv : 0.f);
                }
            }
        }
        __syncthreads();
        __hip_bfloat16* y1p = (__hip_bfloat16*)outp;
        int colr = (tid & 31) * 8;
#pragma unroll
        for (int it = 0; it < 16; it++) {
            int pxr = it * 8 + (tid >> 5);
            int pix = pb + pxr;
            int py = pix >> 8, px = pix & 255;
            f32x4 val = *(f32x4*)&Ct[pxr * 264 + colr];
            *(f32x4*)&y1p[((size_t)(py + 2) * PADW + px + 2) * 256 + colr] = val;
        }
    } else {
        float* outf = (float*)outp;
        float hpart[8][4] = {};
#pragma unroll
        for (int j = 0; j < 4; j++) {
            int oc = (wn * 4 + j) * 16 + m16;
            float bj = bias[oc];
            float wj = wmv[oc];
#pragma unroll
            for (int i = 0; i < 8; i++) {
                f32x4 v = acc[i][j];
#pragma unroll
                for (int e = 0; e < 4; e++) {
                    float tv = v[e] + bj;
                    tv = tv > 0.f ? tv : 0.f;
                    v[e] = tv;
                    hpart[i][e] += wj * tv;
                }
                *(f32x4*)&outf[(size_t)oc * P2 + pb + i * 16 + q * 4] = v;
            }
        }
        // reduce hpart over the 16 m16-lanes (same pixel set), then one atomic per pixel per wave
#pragma unroll
        for (int i = 0; i < 8; i++)
#pragma unroll
            for (int e = 0; e < 4; e++) {
                float s = hpart[i][e];
                s += __shfl_xor(s, 1);
                s += __shfl_xor(s, 2);
                s += __shfl_xor(s, 4);
                s += __shfl_xor(s, 8);
                if (m16 == 0)
                    atomicAdd(&haccum[pb + i * 16 + q * 4 + e], s);
            }
    }
}

// ---------------------------------------------------------------- conv2: 5x5 MFMA (exact R6 core)
// block: 128 threads = 2 waves; each wave 4M (16px strips) x 8N (128 oc).
// A: LDS double-buffer (global_load_lds), barrier only at ic-tile flip.
// B: global->register, one-step ping-pong prefetch (L1/L2-resident weights).
__global__ __launch_bounds__(128, 2) void conv5x5_mfma(const __hip_bfloat16* __restrict__ y1p,
                                                       const __hip_bfloat16* __restrict__ wpk,
                                                       const float* __restrict__ bias,
                                                       __half* __restrict__ pf) {
    __shared__ __align__(16) __hip_bfloat16 Asm[2][12 * 20 * 32];  // 2 x 15360 B
    const int tid = threadIdx.x;
    const int wave = tid >> 6;
    const int lane = tid & 63;
    const int q = lane >> 4;
    const int m16 = lane & 15;
    const int bx = blockIdx.x, by = blockIdx.y, oh = blockIdx.z;

    f32x4 acc[4][8] = {};

    auto stageA = [&](int ict, int buf) {
#pragma unroll
        for (int g = 0; g < 8; g++) {
            int grp = g * 2 + wave;
            if (grp >= 15) break;
            int chb = grp * 64;
            int ch = chb + lane;
            int oct = ch & 3, pl = ch >> 2;
            int pc = pl % 20, pr = pl / 20;
            const __hip_bfloat16* src =
                y1p + (size_t)((by * 8 + pr) * PADW + bx * 16 + pc) * 256 + ict * 32 + oct * 8;
            load16_lds(src, &Asm[buf][chb * 8]);
        }
    };
    auto loadB = [&](int s, frag8* dst) {
        int ict = s / 25, tap = s - ict * 25;
        const __hip_bfloat16* base =
            wpk + ((size_t)((tap * 8 + ict) * 16 + oh * 8) * 64 + lane) * 8;
#pragma unroll
        for (int j = 0; j < 8; j++)
            dst[j] = *(const frag8*)(base + (size_t)j * 512);
    };

    frag8 bA[8], bB[8];
    stageA(0, 0);
    loadB(0, bA);
    int abuf = 0;

    auto step = [&](int s, frag8* bcur, frag8* bnxt) {
        int ict = s / 25, tap = s - ict * 25;
        if (tap == 0) __syncthreads();
        if (s + 1 < 200) loadB(s + 1, bnxt);
        if (tap == 24 && ict < 7) stageA(ict + 1, abuf ^ 1);
        int dy = tap / 5, dx = tap - dy * 5;
        frag8 a[4];
#pragma unroll
        for (int i = 0; i < 4; i++)
            a[i] = *(const frag8*)&Asm[abuf][((wave * 4 + i + dy) * 20 + m16 + dx) * 32 + q * 8];
#pragma unroll
        for (int i = 0; i < 4; i++)
#pragma unroll
            for (int j = 0; j < 8; j++)
                acc[i][j] = __builtin_amdgcn_mfma_f32_16x16x32_bf16(a[i], bcur[j], acc[i][j], 0, 0, 0);
        if (tap == 24) abuf ^= 1;
    };
    for (int s = 0; s < 200; s += 2) { step(s, bA, bB); step(s + 1, bB, bA); }

    // epilogue: fp16 out, 8B stores
#pragma unroll
    for (int j = 0; j < 8; j++) {
        int oc = oh * 128 + j * 16 + m16;
        float bj = bias[oc];
#pragma unroll
        for (int i = 0; i < 4; i++) {
            int r = wave * 4 + i;
            f32x4 v = acc[i][j];
            union { __half h[4]; double d; } u;
#pragma unroll
            for (int e = 0; e < 4; e++) {
                float t = v[e] + bj;
                u.h[e] = __float2half(t > 0.f ? t : 0.f);
            }
            *(double*)&pf[(size_t)oc * P2 + (by * 8 + r) * 256 + bx * 16 + q * 4] = u.d;
        }
    }
}

// ---------------------------------------------------------------- guided filter: streaming separable
__global__ __launch_bounds__(256) void gf_stream(const __half* __restrict__ p,
                                                 const float* __restrict__ guide,
                                                 const float* __restrict__ meanI,
                                                 const float* __restrict__ varI,
                                                 __hip_bfloat16* __restrict__ filt) {
    __shared__ float Prow[260], IProw[260], Arow[260], Brow[260];
    const int t = threadIdx.x;
    const int c = blockIdx.y;
    const int Y0 = blockIdx.x * 64;
    const __half* pc = p + (size_t)c * P2;
    if (t < 4) {
        int e = (t < 2) ? t : 256 + t;
        Prow[e] = 0.f; IProw[e] = 0.f; Arow[e] = 0.f; Brow[e] = 0.f;
    }
    int xlo = (t - 2 > 0) ? t - 2 : 0, xhi = (t + 2 < 255) ? t + 2 : 255;
    const float cxr = 1.0f / (float)(xhi - xlo + 1);
    float hp[5] = {0, 0, 0, 0, 0}, hip[5] = {0, 0, 0, 0, 0};
    float ha[5] = {0, 0, 0, 0, 0}, hb[5] = {0, 0, 0, 0, 0};
    float vp = 0.f, vip = 0.f, va = 0.f, vb = 0.f;
    __syncthreads();
    for (int s = 0; s < 72; s++) {
        int yL = Y0 - 4 + s;
        bool okL = ((unsigned)yL < 256u);
        if (okL) {
            float pv = __half2float(pc[yL * 256 + t]);
            Prow[t + 2] = pv;
            IProw[t + 2] = guide[yL * 256 + t] * pv;
        }
        __syncthreads();
        float hpn = 0.f, hipn = 0.f;
        if (okL) {
            hpn  = Prow[t] + Prow[t + 1] + Prow[t + 2] + Prow[t + 3] + Prow[t + 4];
            hipn = IProw[t] + IProw[t + 1] + IProw[t + 2] + IProw[t + 3] + IProw[t + 4];
        }
        vp += hpn - hp[0];  vip += hipn - hip[0];
        hp[0] = hp[1]; hp[1] = hp[2]; hp[2] = hp[3]; hp[3] = hp[4]; hp[4] = hpn;
        hip[0] = hip[1]; hip[1] = hip[2]; hip[2] = hip[3]; hip[3] = hip[4]; hip[4] = hipn;
        int yA = yL - 2;
        float aV = 0.f, bV = 0.f;
        if ((unsigned)yA < 256u && yA >= Y0 - 2) {
            int ylo = (yA - 2 > 0) ? yA - 2 : 0, yhi = (yA + 2 < 255) ? yA + 2 : 255;
            float inv1 = cxr / (float)(yhi - ylo + 1);
            float mI = meanI[yA * 256 + t], vI = varI[yA * 256 + t];
            float mp = vp * inv1, mip = vip * inv1;
            float cov = mip - mI * mp;
            aV = cov / (vI + 0.01f);
            bV = mp - aV * mI;
        }
        Arow[t + 2] = aV;
        Brow[t + 2] = bV;
        __syncthreads();
        float han = Arow[t] + Arow[t + 1] + Arow[t + 2] + Arow[t + 3] + Arow[t + 4];
        float hbn = Brow[t] + Brow[t + 1] + Brow[t + 2] + Brow[t + 3] + Brow[t + 4];
        va += han - ha[0];  vb += hbn - hb[0];
        ha[0] = ha[1]; ha[1] = ha[2]; ha[2] = ha[3]; ha[3] = ha[4]; ha[4] = han;
        hb[0] = hb[1]; hb[1] = hb[2]; hb[2] = hb[3]; hb[3] = hb[4]; hb[4] = hbn;
        int yo = yL - 4;
        if (yo >= Y0 && yo < Y0 + 64 && (unsigned)yo < 256u) {
            int ylo = (yo - 2 > 0) ? yo - 2 : 0, yhi = (yo + 2 < 255) ? yo + 2 : 255;
            float inv2 = cxr / (float)(yhi - ylo + 1);
            float I = guide[yo * 256 + t];
            filt[(size_t)c * P2 + yo * 256 + t] = __float2bfloat16((va * I + vb) * inv2);
        }
    }
}

// ---------------------------------------------------------------- transpose bf16 [c][p] -> chunk-planar
__global__ void transpose_cp(const __hip_bfloat16* __restrict__ filt,
                             __hip_bfloat16* __restrict__ filtp) {
    __shared__ __hip_bfloat16 T[8][1032];           // pad breaks 8-way read conflicts
    int tid = threadIdx.x;
    int p0 = blockIdx.x * 1024;
    int cg = blockIdx.y;
    for (int i = tid; i < 4096; i += 256) {          // 4B (2px) loads
        int r = i >> 9, pl2 = (i & 511) * 2;
        unsigned v = *(const unsigned*)&filt[(size_t)(cg * 8 + r) * P2 + p0 + pl2];
        *(unsigned*)&T[r][pl2] = v;
    }
    __syncthreads();
    for (int pl = tid; pl < 1024; pl += 256) {
        union { __hip_bfloat16 h[8]; f32x4 v; } u;
#pragma unroll
        for (int j = 0; j < 8; j++) u.h[j] = T[j][pl];
        *(f32x4*)&filtp[((size_t)cg * P2 + p0 + pl) * 8] = u.v;
    }
}

// ---------------------------------------------------------------- sigmoid head finalize
__global__ void sigmoid_head(const float* __restrict__ haccum, const float* __restrict__ bm,
                             float* __restrict__ out) {
    int p = blockIdx.x * 256 + threadIdx.x;
    out[p] = 1.0f / (1.0f + expf(-(haccum[p] + bm[0])));
}

// ---------------------------------------------------------------- launch
extern "C" void kernel_launch(void* const* d_in, const int* in_sizes, int n_in,
                              void* d_out, int out_size, void* d_ws, size_t ws_size,
                              hipStream_t stream) {
    const float* fg   = (const float*)d_in[0];
    const float* bg   = (const float*)d_in[1];
    const float* mask = (const float*)d_in[2];
    const float* feat = (const float*)d_in[3];
    const float* w1   = (const float*)d_in[4];
    const float* b1   = (const float*)d_in[5];
    const float* w2   = (const float*)d_in[6];
    const float* b2   = (const float*)d_in[7];
    const float* w3   = (const float*)d_in[8];
    const float* b3   = (const float*)d_in[9];
    const float* wm   = (const float*)d_in[10];
    const float* bm   = (const float*)d_in[11];
    float* out = (float*)d_out;
    char* w8 = (char*)d_ws;

    __half* pbuf          = (__half*)w8;                         // 33,554,432 B
    __hip_bfloat16* filtp = (__hip_bfloat16*)(w8 + 33554432);    // 33,554,432 B
    __hip_bfloat16* xp    = (__hip_bfloat16*)(w8 + 67108864);    // 37,748,736 B
    __hip_bfloat16* filt  = (__hip_bfloat16*)(w8 + 67108864);    // alias xp
    __hip_bfloat16* y1p   = (__hip_bfloat16*)(w8 + 104857600);   // 34,611,200 B
    __hip_bfloat16* wpk2  = (__hip_bfloat16*)(w8 + 139468800);   // 3,276,800 B
    __hip_bfloat16* wpk1  = (__hip_bfloat16*)(w8 + 142745600);   // 147,456 B
    __hip_bfloat16* wpk3  = (__hip_bfloat16*)(w8 + 142893056);   // 131,072 B
    float* guide  = (float*)(w8 + 143024128);
    float* meanI  = guide + P2;
    float* varI   = meanI + P2;
    float* haccum = varI + P2;

    // 1. upsample + concat -> xp
    upsample_x<<<dim3(256, 36), 256, 0, stream>>>(mask, fg, bg, feat, xp);
    // 2. fused guide + stats
    guide_stats<<<dim3(16, 16), 256, 0, stream>>>(fg, guide, meanI, varI);
    // 3. merged prep (border zero + haccum zero + 3 repacks)
    prep_all<<<1061, 256, 0, stream>>>(w2, w1, w3, wpk2, wpk1, wpk3, y1p, haccum);
    // 4. conv1 (1x1 MFMA, merged oh) -> y1p
    mfma_1x1<0><<<512, 256, 0, stream>>>(xp, wpk1, b1, y1p, 9, nullptr, nullptr);
    // 5. conv2 (5x5 MFMA, R6 core) -> pbuf (fp16 [c][p])
    conv5x5_mfma<<<dim3(16, 32, 2), 128, 0, stream>>>(y1p, wpk2, b2, pbuf);
    // 6. guided filter -> filt (bf16 [c][p])
    gf_stream<<<dim3(4, 256), 256, 0, stream>>>(pbuf, guide, meanI, varI, filt);
    // 7. transpose -> filtp
    transpose_cp<<<dim3(64, 32), 256, 0, stream>>>(filt, filtp);
    // 8. conv3 (1x1 MFMA merged, fused head partials) -> out+P2 & haccum
    mfma_1x1<1><<<512, 256, 0, stream>>>(filtp, wpk3, b3, out + P2, 8, wm, haccum);
    // 9. sigmoid head -> out[0..P2)
    sigmoid_head<<<256, 256, 0, stream>>>(haccum, bm, out);
}